// Round 2
// baseline (1070.136 us; speedup 1.0000x reference)
//
#include <hip/hip_runtime.h>

// RecurrentHyenaBlock on MI355X (gfx950).
//
// Pipeline:
//  prep: pos -> bf16; transpose wp1,wp2,w1,w2 -> bf16 [N,K]; transpose hidden -> hidT[d,t]
//  ln_transpose: xnT[b,d,t] = LN(z)                  (fp32, time-contig for FFT)
//  gemm a: hB = bf16(silu(pos@wp1+bp1))              [2048,4096]
//  gemm b: wfilt[d,t] = (h@wp2+bp2)[t,d]*window[t]   (fp32)
//  fft_filter: wfh[d,k] = rfft_4096(wfilt[d,:])      k=0..2048
//  fft_conv (in-place): znewT[b,d,t] = irfft(wfh*fft(xnT)) + hidT   (fp32)
//  row_stats: mean/rstd per (b,t)
//  untranspose_ln: znew[b,t,d] fp32 + A1 = bf16(LN(znew))
//  gemm c: H2 = bf16(silu(A1@w1+b1))   (two M-halves; H2 reuses buf0)
//  gemm d: out = H2@w2 + b2 + znew
//
// All scratch lives in a static 256 MiB __device__ array (round-1 abort was
// d_ws overflow: old layout needed 344 MiB).

typedef unsigned short u16;
typedef unsigned int u32;
typedef __attribute__((ext_vector_type(8))) short short8;  // 8 x bf16 MFMA fragment
typedef __attribute__((ext_vector_type(4))) float f32x4;   // MFMA accumulator

#define DEVINL __device__ __forceinline__

constexpr size_t MiB = 1ull << 20;
constexpr size_t WS_BYTES = 256 * MiB;
__device__ __attribute__((aligned(256))) char g_ws[WS_BYTES];

constexpr size_t OFF_BUF0  = 0;          // 64 MiB: xnT -> znewT (in-place) -> H2
constexpr size_t OFF_ZNEW  = 64 * MiB;   // 64 MiB fp32 [b,t,d]
constexpr size_t OFF_A1    = 128 * MiB;  // 32 MiB bf16 [16384,1024]
constexpr size_t OFF_HB    = 160 * MiB;  // 16 MiB bf16 [2048,4096]
constexpr size_t OFF_WFH   = 176 * MiB;  // 16.008 MiB float2 [1024,2049]
constexpr size_t OFF_POSB  = 193 * MiB;  // 4 MiB bf16
constexpr size_t OFF_WP1T  = 197 * MiB;  // 8 MiB bf16 [4096,1024]
constexpr size_t OFF_WP2T  = 205 * MiB;  // 8 MiB bf16 [1024,4096]
constexpr size_t OFF_W1T   = 213 * MiB;  // 8 MiB bf16 [4096,1024]
constexpr size_t OFF_W2T   = 221 * MiB;  // 8 MiB bf16 [1024,4096]
constexpr size_t OFF_WFILT = 229 * MiB;  // 8 MiB fp32 [1024,2048]
constexpr size_t OFF_HIDT  = 237 * MiB;  // 8 MiB fp32 [1024,2048]
constexpr size_t OFF_MEAN  = 245 * MiB;  // 64 KiB
constexpr size_t OFF_RSTD  = 245 * MiB + 65536;  // 64 KiB (end < 246 MiB)

DEVINL u16 f2b(float x) {  // fp32 -> bf16 bits, RTNE
  u32 u = __builtin_bit_cast(u32, x);
  return (u16)((u + 0x7fffu + ((u >> 16) & 1u)) >> 16);
}
DEVINL float b2f(u16 h) { u32 u = ((u32)h) << 16; return __builtin_bit_cast(float, u); }
DEVINL float silu_f(float x) { return x / (1.f + __expf(-x)); }

DEVINL void gll16(const u16* g, u16* l) {  // async global->LDS, 16B per lane
  __builtin_amdgcn_global_load_lds((const __attribute__((address_space(1))) u32*)(const void*)g,
                                   (__attribute__((address_space(3))) u32*)(void*)l, 16, 0, 0);
}

// ---------------------------------------------------------------- prep kernels

__global__ __launch_bounds__(256) void conv_bf16(const float* __restrict__ in,
                                                 u16* __restrict__ o) {
  int i = (blockIdx.x * 256 + threadIdx.x) * 4;
  float4 v = *(const float4*)&in[i];
  o[i + 0] = f2b(v.x); o[i + 1] = f2b(v.y); o[i + 2] = f2b(v.z); o[i + 3] = f2b(v.w);
}

// transpose [R,C] fp32 -> [C,R].  OM: 1 = bf16 out, 2 = f32 out
template<int OM>
__global__ __launch_bounds__(256) void transpose_prep(const float* __restrict__ in, int R, int C,
                                                      u16* __restrict__ oh, float* __restrict__ of) {
  __shared__ float tl[64][65];
  int c0 = blockIdx.x * 64, r0 = blockIdx.y * 64;
  int tx = threadIdx.x & 63, ty = threadIdx.x >> 6;
#pragma unroll
  for (int i = 0; i < 16; ++i) {
    int r = ty + i * 4;
    tl[r][tx] = in[(size_t)(r0 + r) * C + c0 + tx];
  }
  __syncthreads();
#pragma unroll
  for (int i = 0; i < 16; ++i) {
    int c = ty + i * 4;
    float v = tl[tx][c];
    size_t o = (size_t)(c0 + c) * R + r0 + tx;
    if constexpr (OM == 1) oh[o] = f2b(v);
    else of[o] = v;
  }
}

// ------------------------------------------------- LayerNorm(z) -> xnT[b,d,t]

__global__ __launch_bounds__(256) void ln_transpose(const float* __restrict__ z,
                                                    const float* __restrict__ g,
                                                    const float* __restrict__ bb,
                                                    float* __restrict__ xnT) {
  int tid = threadIdx.x;
  int b = blockIdx.y, t0 = blockIdx.x * 8;
  __shared__ float tile[8 * 1024];
  __shared__ float smu[8], srs[8], ps[8][4], pq[8][4];
  const float* zp = z + ((size_t)b * 2048 + (size_t)t0) * 1024;
  float s[8], q[8];
#pragma unroll
  for (int r = 0; r < 8; ++r) {
    float4 v = *(const float4*)&zp[r * 1024 + tid * 4];
    *(float4*)&tile[r * 1024 + tid * 4] = v;
    s[r] = v.x + v.y + v.z + v.w;
    q[r] = v.x * v.x + v.y * v.y + v.z * v.z + v.w * v.w;
  }
  int ln = tid & 63, wv = tid >> 6;
#pragma unroll
  for (int r = 0; r < 8; ++r) {
#pragma unroll
    for (int off = 32; off; off >>= 1) { s[r] += __shfl_down(s[r], off); q[r] += __shfl_down(q[r], off); }
    if (ln == 0) { ps[r][wv] = s[r]; pq[r][wv] = q[r]; }
  }
  __syncthreads();
  if (tid < 8) {
    float ss = ps[tid][0] + ps[tid][1] + ps[tid][2] + ps[tid][3];
    float qq = pq[tid][0] + pq[tid][1] + pq[tid][2] + pq[tid][3];
    float mu = ss * (1.f / 1024.f);
    smu[tid] = mu;
    srs[tid] = rsqrtf(qq * (1.f / 1024.f) - mu * mu + 1e-5f);
  }
  __syncthreads();
#pragma unroll
  for (int rep = 0; rep < 4; ++rep) {
    int d = rep * 256 + tid;
    float gg = g[d], b2 = bb[d];
    float o[8];
#pragma unroll
    for (int t = 0; t < 8; ++t) o[t] = (tile[t * 1024 + d] - smu[t]) * srs[t] * gg + b2;
    float* op = xnT + (size_t)b * 2097152 + (size_t)d * 2048 + t0;
    *(float4*)&op[0] = make_float4(o[0], o[1], o[2], o[3]);
    *(float4*)&op[4] = make_float4(o[4], o[5], o[6], o[7]);
  }
}

// -------------------------------------------------------------------- GEMM
// C[M,N] = A[M,K] * B[N,K]^T, bf16 MFMA 16x16x32 (m97 structure).
// MODE: 0 = bias[n]+silu -> outH (bf16)
//       1 = bias[m], *exp(-n*exp(a)) -> outF
//       2 = bias[n]+resid -> outF
template<int BM, int BN, int MODE>
__global__ __launch_bounds__(256) void gemm_bt(
    const u16* __restrict__ A, const u16* __restrict__ B,
    int N, int K,
    const float* __restrict__ bias, const float* __restrict__ resid,
    const float* __restrict__ a_scalar,
    float* __restrict__ outF, u16* __restrict__ outH) {
  constexpr int FM = BM / 32, FN = BN / 32;
  constexpr int TA = BM * 64, TB = BN * 64;
  __shared__ __align__(16) u16 sm[TA + TB];
  u16* sA = sm;
  u16* sB = sm + TA;

  const int tid = threadIdx.x;
  const int lane = tid & 63;
  const int wv = tid >> 6;
  const int wr = wv >> 1, wc = wv & 1;
  const int fr = lane & 15, fq = lane >> 4;
  const int mBase = blockIdx.y * BM;
  const int nBase = blockIdx.x * BN;

  f32x4 acc[FM][FN];
#pragma unroll
  for (int i = 0; i < FM; ++i)
#pragma unroll
    for (int j = 0; j < FN; ++j) acc[i][j] = (f32x4){0.f, 0.f, 0.f, 0.f};

#pragma unroll 1
  for (int k0 = 0; k0 < K; k0 += 64) {
#pragma unroll
    for (int it = 0; it < BM / 32; ++it) {
      int lin = it * 256 + tid, r = lin >> 3, c = (lin & 7) << 3;
      gll16(A + (size_t)(mBase + r) * K + k0 + c, sA + lin * 8);
    }
#pragma unroll
    for (int it = 0; it < BN / 32; ++it) {
      int lin = it * 256 + tid, r = lin >> 3, c = (lin & 7) << 3;
      gll16(B + (size_t)(nBase + r) * K + k0 + c, sB + lin * 8);
    }
    __syncthreads();
#pragma unroll
    for (int kk = 0; kk < 2; ++kk) {
      short8 af[FM], bf[FN];
#pragma unroll
      for (int i = 0; i < FM; ++i)
        af[i] = *(const short8*)&sA[(wr * (BM / 2) + i * 16 + fr) * 64 + kk * 32 + fq * 8];
#pragma unroll
      for (int j = 0; j < FN; ++j)
        bf[j] = *(const short8*)&sB[(wc * (BN / 2) + j * 16 + fr) * 64 + kk * 32 + fq * 8];
#pragma unroll
      for (int i = 0; i < FM; ++i)
#pragma unroll
        for (int j = 0; j < FN; ++j)
          acc[i][j] = __builtin_amdgcn_mfma_f32_16x16x32_bf16(af[i], bf[j], acc[i][j], 0, 0, 0);
    }
    __syncthreads();
  }

  float ea = 0.f;
  if constexpr (MODE == 1) ea = __expf(a_scalar[0]);
#pragma unroll
  for (int i = 0; i < FM; ++i)
#pragma unroll
    for (int j = 0; j < FN; ++j)
#pragma unroll
      for (int r = 0; r < 4; ++r) {
        int gr = mBase + wr * (BM / 2) + i * 16 + fq * 4 + r;
        int gc = nBase + wc * (BN / 2) + j * 16 + fr;
        size_t o = (size_t)gr * (size_t)N + (size_t)gc;
        float x = acc[i][j][r];
        if constexpr (MODE == 0) {
          outH[o] = f2b(silu_f(x + bias[gc]));
        } else if constexpr (MODE == 1) {
          x += bias[gr];
          x *= __expf(-(float)gc * ea);
          outF[o] = x;
        } else {
          outF[o] = x + bias[gc] + resid[o];
        }
      }
}

// -------------------------------------------------------------- FFT (Stockham radix-2)
// 4096-point complex FFT in LDS, 256 threads, 12 stages, ping-pong A<->B,
// result back in first buffer (natural order).  SIGN=-1 fwd, +1 inv (unscaled).
template<int SIGN>
DEVINL void fft4096(float2* x, float2* y, int tid) {
  float c0 = ((float)SIGN) * (6.283185307179586f / 4096.f);
#pragma unroll 1
  for (int st = 0; st < 12; ++st) {
#pragma unroll
    for (int vv = 0; vv < 8; ++vv) {
      int u = vv * 256 + tid;     // u in [0,2048)
      int p = u >> st;
      float2 a = x[u];
      float2 b = x[u + 2048];
      float ang = c0 * (float)p;
      float sn, cs;
      __sincosf(ang, &sn, &cs);
      float mx = a.x - b.x, my = a.y - b.y;
      int base = u + (p << st);
      y[base] = make_float2(a.x + b.x, a.y + b.y);
      y[base + (1 << st)] = make_float2(mx * cs - my * sn, mx * sn + my * cs);
    }
    __syncthreads();
    float2* t = x; x = y; y = t;
    c0 *= 2.f;
  }
}

// filter spectra: wfh[d,k] = rfft(wfilt[d,0:2048] zero-padded to 4096), k<=2048
__global__ __launch_bounds__(256) void fft_filter(const float* __restrict__ wfilt,
                                                  float2* __restrict__ wfh) {
  __shared__ float2 bufA[4096], bufB[4096];
  int tid = threadIdx.x, pr = blockIdx.x;
  int d0 = 2 * pr, d1 = d0 + 1;
  const float* u = wfilt + (size_t)d0 * 2048;
  const float* v = u + 2048;
#pragma unroll
  for (int j = 0; j < 16; ++j) {
    int idx = j * 256 + tid;
    bufA[idx] = (idx < 2048) ? make_float2(u[idx], v[idx]) : make_float2(0.f, 0.f);
  }
  __syncthreads();
  fft4096<-1>(bufA, bufB, tid);
  float2* o0 = wfh + (size_t)d0 * 2049;
  float2* o1 = wfh + (size_t)d1 * 2049;
#pragma unroll
  for (int j = 0; j < 9; ++j) {
    int k = j * 256 + tid;
    if (k <= 2048) {
      int kn = (4096 - k) & 4095;
      float2 Za = bufA[k], Zb = bufA[kn];
      o0[k] = make_float2(0.5f * (Za.x + Zb.x), 0.5f * (Za.y - Zb.y));
      o1[k] = make_float2(0.5f * (Za.y + Zb.y), 0.5f * (Zb.x - Za.x));
    }
  }
}

// conv per (b, d-pair): FFT packed channels, multiply spectra, inverse, +hidden.
// IN-PLACE: writes back over the xnT rows it read.
__global__ __launch_bounds__(256) void fft_conv(float* __restrict__ xnT,
                                                const float2* __restrict__ wfh,
                                                const float* __restrict__ hidT) {
  __shared__ float2 bufA[4096], bufB[4096];
  int tid = threadIdx.x;
  int pr = blockIdx.x, b = blockIdx.y;
  int d0 = 2 * pr, d1 = d0 + 1;
  float* u = xnT + (size_t)b * 2097152 + (size_t)d0 * 2048;
  float* v = u + 2048;
#pragma unroll
  for (int j = 0; j < 16; ++j) {
    int idx = j * 256 + tid;
    bufA[idx] = (idx < 2048) ? make_float2(u[idx], v[idx]) : make_float2(0.f, 0.f);
  }
  __syncthreads();
  fft4096<-1>(bufA, bufB, tid);
  const float2* F0 = wfh + (size_t)d0 * 2049;
  const float2* F1 = wfh + (size_t)d1 * 2049;
#pragma unroll
  for (int j = 0; j < 8; ++j) {
    int k = j * 256 + tid;
    if (k == 0) {
      float2 Z0 = bufA[0], Zh = bufA[2048];
      float2 f00 = F0[0], f10 = F1[0], f0h = F0[2048], f1h = F1[2048];
      float2 P0 = make_float2(Z0.x * f00.x, Z0.x * f00.y);
      float2 P1 = make_float2(Z0.y * f10.x, Z0.y * f10.y);
      bufA[0] = make_float2(P0.x - P1.y, P0.y + P1.x);
      float2 Q0 = make_float2(Zh.x * f0h.x, Zh.x * f0h.y);
      float2 Q1 = make_float2(Zh.y * f1h.x, Zh.y * f1h.y);
      bufA[2048] = make_float2(Q0.x - Q1.y, Q0.y + Q1.x);
    } else {
      int kn = 4096 - k;
      float2 Za = bufA[k], Zb = bufA[kn];
      float2 U = make_float2(0.5f * (Za.x + Zb.x), 0.5f * (Za.y - Zb.y));
      float2 V = make_float2(0.5f * (Za.y + Zb.y), 0.5f * (Zb.x - Za.x));
      float2 f0 = F0[k], f1 = F1[k];
      float2 P0 = make_float2(U.x * f0.x - U.y * f0.y, U.x * f0.y + U.y * f0.x);
      float2 P1 = make_float2(V.x * f1.x - V.y * f1.y, V.x * f1.y + V.y * f1.x);
      bufA[k]  = make_float2(P0.x - P1.y, P0.y + P1.x);
      bufA[kn] = make_float2(P0.x + P1.y, P1.x - P0.y);
    }
  }
  __syncthreads();
  fft4096<1>(bufA, bufB, tid);
  const float sc = 1.f / 4096.f;
  const float* h0 = hidT + (size_t)d0 * 2048;
  const float* h1 = h0 + 2048;
#pragma unroll
  for (int j = 0; j < 8; ++j) {
    int t = j * 256 + tid;
    float2 c = bufA[t];
    u[t] = c.x * sc + h0[t];
    v[t] = c.y * sc + h1[t];
  }
}

// ---------------------------------------------------- znew row stats over d
__global__ __launch_bounds__(256) void row_stats(const float* __restrict__ znewT,
                                                 float* __restrict__ meanb,
                                                 float* __restrict__ rstdb) {
  __shared__ float ss[4][64], sq[4][64];
  int b = blockIdx.y;
  int tl = threadIdx.x & 63, dq = threadIdx.x >> 6;
  int t = blockIdx.x * 64 + tl;
  const float* p = znewT + (size_t)b * 2097152 + (size_t)dq * 256 * 2048 + t;
  float s = 0.f, q = 0.f;
#pragma unroll 4
  for (int d = 0; d < 256; ++d) {
    float v = p[(size_t)d * 2048];
    s += v; q += v * v;
  }
  ss[dq][tl] = s; sq[dq][tl] = q;
  __syncthreads();
  if (threadIdx.x < 64) {
    int tt = blockIdx.x * 64 + threadIdx.x;
    float S = ss[0][threadIdx.x] + ss[1][threadIdx.x] + ss[2][threadIdx.x] + ss[3][threadIdx.x];
    float Q = sq[0][threadIdx.x] + sq[1][threadIdx.x] + sq[2][threadIdx.x] + sq[3][threadIdx.x];
    float mu = S * (1.f / 1024.f);
    meanb[b * 2048 + tt] = mu;
    rstdb[b * 2048 + tt] = rsqrtf(Q * (1.f / 1024.f) - mu * mu + 1e-5f);
  }
}

// ---------------------- znewT -> znew[b,t,d] fp32 + A1 = bf16(LN(znew))
__global__ __launch_bounds__(256) void untranspose_ln(const float* __restrict__ znewT,
                                                      const float* __restrict__ meanb,
                                                      const float* __restrict__ rstdb,
                                                      const float* __restrict__ g,
                                                      const float* __restrict__ bb,
                                                      float* __restrict__ znew,
                                                      u16* __restrict__ A1) {
  __shared__ float tl[64][65];
  int b = blockIdx.z;
  int t0 = blockIdx.y * 64, d0 = blockIdx.x * 64;
  int tx = threadIdx.x & 63, ty = threadIdx.x >> 6;
  const float* ip = znewT + (size_t)b * 2097152 + (size_t)d0 * 2048 + t0;
#pragma unroll
  for (int i = 0; i < 16; ++i) {
    int d = ty + i * 4;
    tl[d][tx] = ip[(size_t)d * 2048 + tx];
  }
  __syncthreads();
  int m0 = b * 2048 + t0;
  float gg = g[d0 + tx], b2 = bb[d0 + tx];
#pragma unroll
  for (int i = 0; i < 16; ++i) {
    int t = ty + i * 4;
    float v = tl[tx][t];
    float mu = meanb[m0 + t], rs = rstdb[m0 + t];
    size_t o = (size_t)(m0 + t) * 1024 + d0 + tx;
    znew[o] = v;
    A1[o] = f2b((v - mu) * rs * gg + b2);
  }
}

// ---------------------------------------------------------------- launch

extern "C" void kernel_launch(void* const* d_in, const int* in_sizes, int n_in,
                              void* d_out, int out_size, void* d_ws, size_t ws_size,
                              hipStream_t stream) {
  (void)in_sizes; (void)n_in; (void)out_size; (void)ws_size;
  const float* z   = (const float*)d_in[0];
  const float* pos = (const float*)d_in[1];
  const float* a   = (const float*)d_in[2];
  const float* hid = (const float*)d_in[3];
  const float* lng = (const float*)d_in[4];
  const float* lnb = (const float*)d_in[5];
  const float* wp1 = (const float*)d_in[6];
  const float* bp1 = (const float*)d_in[7];
  const float* wp2 = (const float*)d_in[8];
  const float* bp2 = (const float*)d_in[9];
  const float* w1  = (const float*)d_in[10];
  const float* b1  = (const float*)d_in[11];
  const float* w2  = (const float*)d_in[12];
  const float* b2  = (const float*)d_in[13];
  float* out = (float*)d_out;

  char* ws = nullptr;
  if (hipGetSymbolAddress((void**)&ws, HIP_SYMBOL(g_ws)) != hipSuccess || ws == nullptr)
    ws = (char*)d_ws;  // fallback (deterministic)

  float*  buf0  = (float*)(ws + OFF_BUF0);   // xnT -> znewT -> H2
  float*  znew  = (float*)(ws + OFF_ZNEW);
  u16*    A1    = (u16*)  (ws + OFF_A1);
  u16*    hB    = (u16*)  (ws + OFF_HB);
  float2* wfh   = (float2*)(ws + OFF_WFH);
  u16*    posB  = (u16*)  (ws + OFF_POSB);
  u16*    wp1t  = (u16*)  (ws + OFF_WP1T);
  u16*    wp2t  = (u16*)  (ws + OFF_WP2T);
  u16*    w1t   = (u16*)  (ws + OFF_W1T);
  u16*    w2t   = (u16*)  (ws + OFF_W2T);
  float*  wfilt = (float*)(ws + OFF_WFILT);
  float*  hidT  = (float*)(ws + OFF_HIDT);
  float*  meanb = (float*)(ws + OFF_MEAN);
  float*  rstdb = (float*)(ws + OFF_RSTD);
  u16*    H2    = (u16*)  (ws + OFF_BUF0);

  // prep
  conv_bf16<<<2048, 256, 0, stream>>>(pos, posB);
  transpose_prep<1><<<dim3(64, 16), 256, 0, stream>>>(wp1, 1024, 4096, wp1t, nullptr);
  transpose_prep<1><<<dim3(16, 64), 256, 0, stream>>>(wp2, 4096, 1024, wp2t, nullptr);
  transpose_prep<1><<<dim3(64, 16), 256, 0, stream>>>(w1, 1024, 4096, w1t, nullptr);
  transpose_prep<1><<<dim3(16, 64), 256, 0, stream>>>(w2, 4096, 1024, w2t, nullptr);
  transpose_prep<2><<<dim3(16, 32), 256, 0, stream>>>(hid, 2048, 1024, nullptr, hidT);

  // LN(z) -> xnT
  ln_transpose<<<dim3(256, 8), 256, 0, stream>>>(z, lng, lnb, buf0);

  // filter FFN
  gemm_bt<128, 128, 0><<<dim3(32, 16), 256, 0, stream>>>(
      posB, wp1t, 4096, 1024, bp1, nullptr, nullptr, nullptr, hB);
  gemm_bt<64, 64, 1><<<dim3(32, 16), 256, 0, stream>>>(
      wp2t, hB, 2048, 4096, bp2, nullptr, a, wfilt, nullptr);

  // FFT conv (in-place over xnT)
  fft_filter<<<512, 256, 0, stream>>>(wfilt, wfh);
  fft_conv<<<dim3(512, 8), 256, 0, stream>>>(buf0, wfh, hidT);

  // stats + transpose + LN
  row_stats<<<dim3(32, 8), 256, 0, stream>>>(buf0, meanb, rstdb);
  untranspose_ln<<<dim3(16, 32, 8), 256, 0, stream>>>(buf0, meanb, rstdb, lng, lnb, znew, A1);

  // big FFN in two M-halves (H2 reuses buf0, dead after untranspose)
  for (int h = 0; h < 2; ++h) {
    const u16* Ap = A1 + (size_t)h * 8192 * 1024;
    const float* zp = znew + (size_t)h * 8192 * 1024;
    float* op = out + (size_t)h * 8192 * 1024;
    gemm_bt<128, 128, 0><<<dim3(32, 64), 256, 0, stream>>>(
        Ap, w1t, 4096, 1024, b1, nullptr, nullptr, nullptr, H2);
    gemm_bt<128, 128, 2><<<dim3(8, 64), 256, 0, stream>>>(
        H2, w2t, 1024, 4096, b2, zp, nullptr, op, nullptr);
  }
}

// Round 3
// 947.390 us; speedup vs baseline: 1.1296x; 1.1296x over previous
//
#include <hip/hip_runtime.h>

// RecurrentHyenaBlock on MI355X (gfx950).
//
// Pipeline:
//  prep: pos -> bf16; transpose wp1,wp2,w1,w2 -> bf16 [N,K]; transpose hidden -> hidT[d,t]
//  zstats: mean/rstd of z rows          transpose_ln: xnT[b,d,t] = LN(z) (coalesced both sides)
//  gemm a: hB = bf16(silu(pos@wp1+bp1))              [2048,4096]
//  gemm b: wfilt[d,t] = (h@wp2+bp2)[t,d]*window[t]   (fp32)
//  fft_filter: wfh[d,k] = rfft_4096(wfilt[d,:])      k=0..2048
//  fft_conv (in-place): znewT[b,d,t] = irfft(wfh*fft(xnT)) + hidT   (fp32)
//  row_stats: mean/rstd per (b,t)
//  untranspose_ln: znew[b,t,d] fp32 + A1 = bf16(LN(znew))
//  gemm c: H2 = bf16(silu(A1@w1+b1))   (two M-halves; H2 reuses buf0)
//  gemm d: out = H2@w2 + b2 + znew
//
// FFT: radix-16 Stockham (3 stages), 16-pt DFT in registers, padded LDS
// slot(e)=e+(e>>4) so all stage reads/writes hit the 4-cycle b64 minimum.

typedef unsigned short u16;
typedef unsigned int u32;
typedef __attribute__((ext_vector_type(8))) short short8;  // 8 x bf16 MFMA fragment
typedef __attribute__((ext_vector_type(4))) float f32x4;   // MFMA accumulator

#define DEVINL __device__ __forceinline__

constexpr size_t MiB = 1ull << 20;
constexpr size_t WS_BYTES = 256 * MiB;
__device__ __attribute__((aligned(256))) char g_ws[WS_BYTES];

constexpr size_t OFF_BUF0  = 0;          // 64 MiB: xnT -> znewT (in-place) -> H2
constexpr size_t OFF_ZNEW  = 64 * MiB;   // 64 MiB fp32 [b,t,d]
constexpr size_t OFF_A1    = 128 * MiB;  // 32 MiB bf16 [16384,1024]
constexpr size_t OFF_HB    = 160 * MiB;  // 16 MiB bf16 [2048,4096]
constexpr size_t OFF_WFH   = 176 * MiB;  // 16.008 MiB float2 [1024,2049]
constexpr size_t OFF_POSB  = 193 * MiB;  // 4 MiB bf16
constexpr size_t OFF_WP1T  = 197 * MiB;  // 8 MiB bf16 [4096,1024]
constexpr size_t OFF_WP2T  = 205 * MiB;  // 8 MiB bf16 [1024,4096]
constexpr size_t OFF_W1T   = 213 * MiB;  // 8 MiB bf16 [4096,1024]
constexpr size_t OFF_W2T   = 221 * MiB;  // 8 MiB bf16 [1024,4096]
constexpr size_t OFF_WFILT = 229 * MiB;  // 8 MiB fp32 [1024,2048]
constexpr size_t OFF_HIDT  = 237 * MiB;  // 8 MiB fp32 [1024,2048]
constexpr size_t OFF_MEAN  = 245 * MiB;  // 64 KiB (reused: z-stats then znew-stats)
constexpr size_t OFF_RSTD  = 245 * MiB + 65536;  // 64 KiB

DEVINL u16 f2b(float x) {  // fp32 -> bf16 bits, RTNE
  u32 u = __builtin_bit_cast(u32, x);
  return (u16)((u + 0x7fffu + ((u >> 16) & 1u)) >> 16);
}
DEVINL float b2f(u16 h) { u32 u = ((u32)h) << 16; return __builtin_bit_cast(float, u); }
DEVINL float silu_f(float x) { return x / (1.f + __expf(-x)); }

DEVINL void gll16(const u16* g, u16* l) {  // async global->LDS, 16B per lane
  __builtin_amdgcn_global_load_lds((const __attribute__((address_space(1))) u32*)(const void*)g,
                                   (__attribute__((address_space(3))) u32*)(void*)l, 16, 0, 0);
}

// ---------------------------------------------------------------- prep kernels

__global__ __launch_bounds__(256) void conv_bf16(const float* __restrict__ in,
                                                 u16* __restrict__ o) {
  int i = (blockIdx.x * 256 + threadIdx.x) * 4;
  float4 v = *(const float4*)&in[i];
  o[i + 0] = f2b(v.x); o[i + 1] = f2b(v.y); o[i + 2] = f2b(v.z); o[i + 3] = f2b(v.w);
}

// transpose [R,C] fp32 -> [C,R].  OM: 1 = bf16 out, 2 = f32 out
template<int OM>
__global__ __launch_bounds__(256) void transpose_prep(const float* __restrict__ in, int R, int C,
                                                      u16* __restrict__ oh, float* __restrict__ of) {
  __shared__ float tl[64][65];
  int c0 = blockIdx.x * 64, r0 = blockIdx.y * 64;
  int tx = threadIdx.x & 63, ty = threadIdx.x >> 6;
#pragma unroll
  for (int i = 0; i < 16; ++i) {
    int r = ty + i * 4;
    tl[r][tx] = in[(size_t)(r0 + r) * C + c0 + tx];
  }
  __syncthreads();
#pragma unroll
  for (int i = 0; i < 16; ++i) {
    int c = ty + i * 4;
    float v = tl[tx][c];
    size_t o = (size_t)(c0 + c) * R + r0 + tx;
    if constexpr (OM == 1) oh[o] = f2b(v);
    else of[o] = v;
  }
}

// ------------------------------------------- z row stats (per b*2048+t row)
__global__ __launch_bounds__(256) void zstats(const float* __restrict__ z,
                                              float* __restrict__ meanb,
                                              float* __restrict__ rstdb) {
  int row = blockIdx.x * 4 + (threadIdx.x >> 6);
  int ln = threadIdx.x & 63;
  const float* p = z + (size_t)row * 1024;
  float s = 0.f, q = 0.f;
#pragma unroll
  for (int i = 0; i < 4; ++i) {
    float4 v = *(const float4*)&p[ln * 4 + i * 256];
    s += v.x + v.y + v.z + v.w;
    q += v.x * v.x + v.y * v.y + v.z * v.z + v.w * v.w;
  }
#pragma unroll
  for (int off = 32; off; off >>= 1) { s += __shfl_down(s, off); q += __shfl_down(q, off); }
  if (ln == 0) {
    float mu = s * (1.f / 1024.f);
    meanb[row] = mu;
    rstdb[row] = rsqrtf(q * (1.f / 1024.f) - mu * mu + 1e-5f);
  }
}

// ----------------- xnT[b,d,t] = LN(z) via 64x64 tiles (coalesced both sides)
__global__ __launch_bounds__(256) void transpose_ln(const float* __restrict__ z,
                                                    const float* __restrict__ meanb,
                                                    const float* __restrict__ rstdb,
                                                    const float* __restrict__ g,
                                                    const float* __restrict__ bb,
                                                    float* __restrict__ xnT) {
  __shared__ float tl[64][65];
  int b = blockIdx.z;
  int t0 = blockIdx.y * 64, d0 = blockIdx.x * 64;
  int tx = threadIdx.x & 63, ty = threadIdx.x >> 6;
#pragma unroll
  for (int i = 0; i < 16; ++i) {
    int t = ty + i * 4;
    tl[t][tx] = z[((size_t)b * 2048 + t0 + t) * 1024 + d0 + tx];
  }
  __syncthreads();
  float mu = meanb[b * 2048 + t0 + tx], rs = rstdb[b * 2048 + t0 + tx];
#pragma unroll
  for (int i = 0; i < 16; ++i) {
    int d = ty + i * 4;
    float v = tl[tx][d];  // z[t0+tx][d0+d]
    xnT[(size_t)b * 2097152 + (size_t)(d0 + d) * 2048 + t0 + tx] =
        (v - mu) * rs * g[d0 + d] + bb[d0 + d];
  }
}

// -------------------------------------------------------------------- GEMM
// C[M,N] = A[M,K] * B[N,K]^T, bf16 MFMA 16x16x32 (m97 structure).
// MODE: 0 = bias[n]+silu -> outH (bf16)
//       1 = bias[m], *exp(-n*exp(a)) -> outF
//       2 = bias[n]+resid -> outF
template<int BM, int BN, int MODE>
__global__ __launch_bounds__(256) void gemm_bt(
    const u16* __restrict__ A, const u16* __restrict__ B,
    int N, int K,
    const float* __restrict__ bias, const float* __restrict__ resid,
    const float* __restrict__ a_scalar,
    float* __restrict__ outF, u16* __restrict__ outH) {
  constexpr int FM = BM / 32, FN = BN / 32;
  constexpr int TA = BM * 64, TB = BN * 64;
  __shared__ __align__(16) u16 sm[TA + TB];
  u16* sA = sm;
  u16* sB = sm + TA;

  const int tid = threadIdx.x;
  const int lane = tid & 63;
  const int wv = tid >> 6;
  const int wr = wv >> 1, wc = wv & 1;
  const int fr = lane & 15, fq = lane >> 4;
  const int mBase = blockIdx.y * BM;
  const int nBase = blockIdx.x * BN;

  f32x4 acc[FM][FN];
#pragma unroll
  for (int i = 0; i < FM; ++i)
#pragma unroll
    for (int j = 0; j < FN; ++j) acc[i][j] = (f32x4){0.f, 0.f, 0.f, 0.f};

#pragma unroll 1
  for (int k0 = 0; k0 < K; k0 += 64) {
#pragma unroll
    for (int it = 0; it < BM / 32; ++it) {
      int lin = it * 256 + tid, r = lin >> 3, c = (lin & 7) << 3;
      gll16(A + (size_t)(mBase + r) * K + k0 + c, sA + lin * 8);
    }
#pragma unroll
    for (int it = 0; it < BN / 32; ++it) {
      int lin = it * 256 + tid, r = lin >> 3, c = (lin & 7) << 3;
      gll16(B + (size_t)(nBase + r) * K + k0 + c, sB + lin * 8);
    }
    __syncthreads();
#pragma unroll
    for (int kk = 0; kk < 2; ++kk) {
      short8 af[FM], bf[FN];
#pragma unroll
      for (int i = 0; i < FM; ++i)
        af[i] = *(const short8*)&sA[(wr * (BM / 2) + i * 16 + fr) * 64 + kk * 32 + fq * 8];
#pragma unroll
      for (int j = 0; j < FN; ++j)
        bf[j] = *(const short8*)&sB[(wc * (BN / 2) + j * 16 + fr) * 64 + kk * 32 + fq * 8];
#pragma unroll
      for (int i = 0; i < FM; ++i)
#pragma unroll
        for (int j = 0; j < FN; ++j)
          acc[i][j] = __builtin_amdgcn_mfma_f32_16x16x32_bf16(af[i], bf[j], acc[i][j], 0, 0, 0);
    }
    __syncthreads();
  }

  float ea = 0.f;
  if constexpr (MODE == 1) ea = __expf(a_scalar[0]);
#pragma unroll
  for (int i = 0; i < FM; ++i)
#pragma unroll
    for (int j = 0; j < FN; ++j)
#pragma unroll
      for (int r = 0; r < 4; ++r) {
        int gr = mBase + wr * (BM / 2) + i * 16 + fq * 4 + r;
        int gc = nBase + wc * (BN / 2) + j * 16 + fr;
        size_t o = (size_t)gr * (size_t)N + (size_t)gc;
        float x = acc[i][j][r];
        if constexpr (MODE == 0) {
          outH[o] = f2b(silu_f(x + bias[gc]));
        } else if constexpr (MODE == 1) {
          x += bias[gr];
          x *= __expf(-(float)gc * ea);
          outF[o] = x;
        } else {
          outF[o] = x + bias[gc] + resid[o];
        }
      }
}

// ----------------------------------------------- FFT: radix-16 Stockham
// LDS layout pad: slot(e) = e + (e>>4)  (4352 float2 per buffer)
#define SLOT(e) ((e) + ((e) >> 4))
constexpr int FBUF = 4352;

DEVINL float2 cadd(float2 a, float2 b) { return make_float2(a.x + b.x, a.y + b.y); }
DEVINL float2 csub(float2 a, float2 b) { return make_float2(a.x - b.x, a.y - b.y); }
DEVINL float2 cmul(float2 a, float2 b) {
  return make_float2(a.x * b.x - a.y * b.y, a.x * b.y + a.y * b.x);
}
template<int SGN> DEVINL float2 cmuli(float2 a) {  // a * (SGN*i)
  return (SGN < 0) ? make_float2(a.y, -a.x) : make_float2(-a.y, a.x);
}

// in-register 16-point DFT: v[k] = sum_n v[n] * exp(SGN*2*pi*i*n*k/16)
template<int SGN>
DEVINL void dft16(float2 v[16]) {
  float2 T[16];
#pragma unroll
  for (int n1 = 0; n1 < 4; ++n1) {
    float2 a = v[n1], b = v[n1 + 4], c = v[n1 + 8], d = v[n1 + 12];
    float2 t0 = cadd(a, c), t1 = csub(a, c), t2 = cadd(b, d), t3 = cmuli<SGN>(csub(b, d));
    T[n1 * 4 + 0] = cadd(t0, t2);
    T[n1 * 4 + 2] = csub(t0, t2);
    T[n1 * 4 + 1] = cadd(t1, t3);
    T[n1 * 4 + 3] = csub(t1, t3);
  }
  // twiddle T[n1*4+k2] *= W16^(SGN*n1*k2)
  constexpr float C1 = 0.92387953251128675613f, S1 = 0.38268343236508977173f;
  constexpr float C2 = 0.70710678118654752440f;
  const float sg = (float)SGN;
  const float2 W1 = make_float2(C1, sg * S1);
  const float2 W2 = make_float2(C2, sg * C2);
  const float2 W3 = make_float2(S1, sg * C1);
  const float2 W6 = make_float2(-C2, sg * C2);
  const float2 W9 = make_float2(-C1, sg * -S1);
  T[5] = cmul(T[5], W1);
  T[6] = cmul(T[6], W2);
  T[7] = cmul(T[7], W3);
  T[9] = cmul(T[9], W2);
  T[10] = cmuli<SGN>(T[10]);  // W4 = SGN*i
  T[11] = cmul(T[11], W6);
  T[13] = cmul(T[13], W3);
  T[14] = cmul(T[14], W6);
  T[15] = cmul(T[15], W9);
#pragma unroll
  for (int k2 = 0; k2 < 4; ++k2) {
    float2 a = T[k2], b = T[4 + k2], c = T[8 + k2], d = T[12 + k2];
    float2 t0 = cadd(a, c), t1 = csub(a, c), t2 = cadd(b, d), t3 = cmuli<SGN>(csub(b, d));
    v[0 * 4 + k2] = cadd(t0, t2);
    v[2 * 4 + k2] = csub(t0, t2);
    v[1 * 4 + k2] = cadd(t1, t3);
    v[3 * 4 + k2] = csub(t1, t3);
  }
}

// 4096-pt complex FFT, 3 radix-16 Stockham stages, 256 threads.
// Input in x (natural order, SLOT layout); RESULT IN y.  Each stage ends with
// a barrier.  SIGN=-1 fwd, +1 inv (unscaled).
template<int SGN>
DEVINL void fft4096_r16(float2* x, float2* y, int tid) {
#pragma unroll
  for (int st = 0; st < 3; ++st) {
    const int S = 1 << (4 * st);
    const int u = tid;
    float2 v[16];
#pragma unroll
    for (int r = 0; r < 16; ++r) v[r] = x[SLOT(u + 256 * r)];
    dft16<SGN>(v);
    if (st < 2) {
      float th = ((float)SGN) * (6.28318530717958647693f / 4096.f) * (float)(u & ~(S - 1));
      float sn, cs;
      __sincosf(th, &sn, &cs);
      float2 w = make_float2(cs, sn), wk = w;
#pragma unroll
      for (int k = 1; k < 16; ++k) { v[k] = cmul(v[k], wk); wk = cmul(wk, w); }
    }
    const int p = u >> (4 * st);
    const int base = u + p * S * 15;
#pragma unroll
    for (int k = 0; k < 16; ++k) y[SLOT(base + S * k)] = v[k];
    __syncthreads();
    float2* t = x; x = y; y = t;
  }
}

// filter spectra: wfh[d,k] = rfft(wfilt[d,0:2048] zero-padded to 4096), k<=2048
__global__ __launch_bounds__(256) void fft_filter(const float* __restrict__ wfilt,
                                                  float2* __restrict__ wfh) {
  __shared__ float2 bufA[FBUF], bufB[FBUF];
  int tid = threadIdx.x, pr = blockIdx.x;
  int d0 = 2 * pr, d1 = d0 + 1;
  const float* u = wfilt + (size_t)d0 * 2048;
  const float* v = u + 2048;
#pragma unroll
  for (int j = 0; j < 16; ++j) {
    int idx = j * 256 + tid;
    bufA[SLOT(idx)] = (idx < 2048) ? make_float2(u[idx], v[idx]) : make_float2(0.f, 0.f);
  }
  __syncthreads();
  fft4096_r16<-1>(bufA, bufB, tid);  // result in bufB
  float2* o0 = wfh + (size_t)d0 * 2049;
  float2* o1 = wfh + (size_t)d1 * 2049;
#pragma unroll
  for (int j = 0; j < 9; ++j) {
    int k = j * 256 + tid;
    if (k <= 2048) {
      int kn = (4096 - k) & 4095;
      float2 Za = bufB[SLOT(k)], Zb = bufB[SLOT(kn)];
      o0[k] = make_float2(0.5f * (Za.x + Zb.x), 0.5f * (Za.y - Zb.y));
      o1[k] = make_float2(0.5f * (Za.y + Zb.y), 0.5f * (Zb.x - Za.x));
    }
  }
}

// conv per (b, d-pair): FFT packed channels, multiply spectra, inverse, +hidden.
// IN-PLACE: writes back over the xnT rows it read.
__global__ __launch_bounds__(256) void fft_conv(float* __restrict__ xnT,
                                                const float2* __restrict__ wfh,
                                                const float* __restrict__ hidT) {
  __shared__ float2 bufA[FBUF], bufB[FBUF];
  int tid = threadIdx.x;
  int pr = blockIdx.x, b = blockIdx.y;
  int d0 = 2 * pr, d1 = d0 + 1;
  float* u = xnT + (size_t)b * 2097152 + (size_t)d0 * 2048;
  float* v = u + 2048;
#pragma unroll
  for (int j = 0; j < 16; ++j) {
    int idx = j * 256 + tid;
    bufA[SLOT(idx)] = (idx < 2048) ? make_float2(u[idx], v[idx]) : make_float2(0.f, 0.f);
  }
  __syncthreads();
  fft4096_r16<-1>(bufA, bufB, tid);  // spectrum in bufB
  const float2* F0 = wfh + (size_t)d0 * 2049;
  const float2* F1 = wfh + (size_t)d1 * 2049;
#pragma unroll
  for (int j = 0; j < 8; ++j) {
    int k = j * 256 + tid;
    if (k == 0) {
      float2 Z0 = bufB[SLOT(0)], Zh = bufB[SLOT(2048)];
      float2 f00 = F0[0], f10 = F1[0], f0h = F0[2048], f1h = F1[2048];
      float2 P0 = make_float2(Z0.x * f00.x, Z0.x * f00.y);
      float2 P1 = make_float2(Z0.y * f10.x, Z0.y * f10.y);
      bufB[SLOT(0)] = make_float2(P0.x - P1.y, P0.y + P1.x);
      float2 Q0 = make_float2(Zh.x * f0h.x, Zh.x * f0h.y);
      float2 Q1 = make_float2(Zh.y * f1h.x, Zh.y * f1h.y);
      bufB[SLOT(2048)] = make_float2(Q0.x - Q1.y, Q0.y + Q1.x);
    } else {
      int kn = 4096 - k;
      float2 Za = bufB[SLOT(k)], Zb = bufB[SLOT(kn)];
      float2 U = make_float2(0.5f * (Za.x + Zb.x), 0.5f * (Za.y - Zb.y));
      float2 V = make_float2(0.5f * (Za.y + Zb.y), 0.5f * (Zb.x - Za.x));
      float2 f0 = F0[k], f1 = F1[k];
      float2 P0 = make_float2(U.x * f0.x - U.y * f0.y, U.x * f0.y + U.y * f0.x);
      float2 P1 = make_float2(V.x * f1.x - V.y * f1.y, V.x * f1.y + V.y * f1.x);
      bufB[SLOT(k)]  = make_float2(P0.x - P1.y, P0.y + P1.x);
      bufB[SLOT(kn)] = make_float2(P0.x + P1.y, P1.x - P0.y);
    }
  }
  __syncthreads();
  fft4096_r16<1>(bufB, bufA, tid);  // time domain in bufA
  const float sc = 1.f / 4096.f;
  const float* h0 = hidT + (size_t)d0 * 2048;
  const float* h1 = h0 + 2048;
#pragma unroll
  for (int j = 0; j < 8; ++j) {
    int t = j * 256 + tid;
    float2 c = bufA[SLOT(t)];
    u[t] = c.x * sc + h0[t];
    v[t] = c.y * sc + h1[t];
  }
}

// ---------------------------------------------------- znew row stats over d
__global__ __launch_bounds__(256) void row_stats(const float* __restrict__ znewT,
                                                 float* __restrict__ meanb,
                                                 float* __restrict__ rstdb) {
  __shared__ float ss[4][64], sq[4][64];
  int b = blockIdx.y;
  int tl = threadIdx.x & 63, dq = threadIdx.x >> 6;
  int t = blockIdx.x * 64 + tl;
  const float* p = znewT + (size_t)b * 2097152 + (size_t)dq * 256 * 2048 + t;
  float s = 0.f, q = 0.f;
#pragma unroll 4
  for (int d = 0; d < 256; ++d) {
    float v = p[(size_t)d * 2048];
    s += v; q += v * v;
  }
  ss[dq][tl] = s; sq[dq][tl] = q;
  __syncthreads();
  if (threadIdx.x < 64) {
    int tt = blockIdx.x * 64 + threadIdx.x;
    float S = ss[0][threadIdx.x] + ss[1][threadIdx.x] + ss[2][threadIdx.x] + ss[3][threadIdx.x];
    float Q = sq[0][threadIdx.x] + sq[1][threadIdx.x] + sq[2][threadIdx.x] + sq[3][threadIdx.x];
    float mu = S * (1.f / 1024.f);
    meanb[b * 2048 + tt] = mu;
    rstdb[b * 2048 + tt] = rsqrtf(Q * (1.f / 1024.f) - mu * mu + 1e-5f);
  }
}

// ---------------------- znewT -> znew[b,t,d] fp32 + A1 = bf16(LN(znew))
__global__ __launch_bounds__(256) void untranspose_ln(const float* __restrict__ znewT,
                                                      const float* __restrict__ meanb,
                                                      const float* __restrict__ rstdb,
                                                      const float* __restrict__ g,
                                                      const float* __restrict__ bb,
                                                      float* __restrict__ znew,
                                                      u16* __restrict__ A1) {
  __shared__ float tl[64][65];
  int b = blockIdx.z;
  int t0 = blockIdx.y * 64, d0 = blockIdx.x * 64;
  int tx = threadIdx.x & 63, ty = threadIdx.x >> 6;
  const float* ip = znewT + (size_t)b * 2097152 + (size_t)d0 * 2048 + t0;
#pragma unroll
  for (int i = 0; i < 16; ++i) {
    int d = ty + i * 4;
    tl[d][tx] = ip[(size_t)d * 2048 + tx];
  }
  __syncthreads();
  int m0 = b * 2048 + t0;
  float gg = g[d0 + tx], b2 = bb[d0 + tx];
#pragma unroll
  for (int i = 0; i < 16; ++i) {
    int t = ty + i * 4;
    float v = tl[tx][t];
    float mu = meanb[m0 + t], rs = rstdb[m0 + t];
    size_t o = (size_t)(m0 + t) * 1024 + d0 + tx;
    znew[o] = v;
    A1[o] = f2b((v - mu) * rs * gg + b2);
  }
}

// ---------------------------------------------------------------- launch

extern "C" void kernel_launch(void* const* d_in, const int* in_sizes, int n_in,
                              void* d_out, int out_size, void* d_ws, size_t ws_size,
                              hipStream_t stream) {
  (void)in_sizes; (void)n_in; (void)out_size; (void)ws_size;
  const float* z   = (const float*)d_in[0];
  const float* pos = (const float*)d_in[1];
  const float* a   = (const float*)d_in[2];
  const float* hid = (const float*)d_in[3];
  const float* lng = (const float*)d_in[4];
  const float* lnb = (const float*)d_in[5];
  const float* wp1 = (const float*)d_in[6];
  const float* bp1 = (const float*)d_in[7];
  const float* wp2 = (const float*)d_in[8];
  const float* bp2 = (const float*)d_in[9];
  const float* w1  = (const float*)d_in[10];
  const float* b1  = (const float*)d_in[11];
  const float* w2  = (const float*)d_in[12];
  const float* b2  = (const float*)d_in[13];
  float* out = (float*)d_out;

  char* ws = nullptr;
  if (hipGetSymbolAddress((void**)&ws, HIP_SYMBOL(g_ws)) != hipSuccess || ws == nullptr)
    ws = (char*)d_ws;  // fallback (deterministic)

  float*  buf0  = (float*)(ws + OFF_BUF0);   // xnT -> znewT -> H2
  float*  znew  = (float*)(ws + OFF_ZNEW);
  u16*    A1    = (u16*)  (ws + OFF_A1);
  u16*    hB    = (u16*)  (ws + OFF_HB);
  float2* wfh   = (float2*)(ws + OFF_WFH);
  u16*    posB  = (u16*)  (ws + OFF_POSB);
  u16*    wp1t  = (u16*)  (ws + OFF_WP1T);
  u16*    wp2t  = (u16*)  (ws + OFF_WP2T);
  u16*    w1t   = (u16*)  (ws + OFF_W1T);
  u16*    w2t   = (u16*)  (ws + OFF_W2T);
  float*  wfilt = (float*)(ws + OFF_WFILT);
  float*  hidT  = (float*)(ws + OFF_HIDT);
  float*  meanb = (float*)(ws + OFF_MEAN);
  float*  rstdb = (float*)(ws + OFF_RSTD);
  u16*    H2    = (u16*)  (ws + OFF_BUF0);

  // prep
  conv_bf16<<<2048, 256, 0, stream>>>(pos, posB);
  transpose_prep<1><<<dim3(64, 16), 256, 0, stream>>>(wp1, 1024, 4096, wp1t, nullptr);
  transpose_prep<1><<<dim3(16, 64), 256, 0, stream>>>(wp2, 4096, 1024, wp2t, nullptr);
  transpose_prep<1><<<dim3(64, 16), 256, 0, stream>>>(w1, 1024, 4096, w1t, nullptr);
  transpose_prep<1><<<dim3(16, 64), 256, 0, stream>>>(w2, 4096, 1024, w2t, nullptr);
  transpose_prep<2><<<dim3(16, 32), 256, 0, stream>>>(hid, 2048, 1024, nullptr, hidT);

  // LN(z) -> xnT (stats then tiled transpose-normalize)
  zstats<<<4096, 256, 0, stream>>>(z, meanb, rstdb);
  transpose_ln<<<dim3(16, 32, 8), 256, 0, stream>>>(z, meanb, rstdb, lng, lnb, buf0);

  // filter FFN
  gemm_bt<128, 128, 0><<<dim3(32, 16), 256, 0, stream>>>(
      posB, wp1t, 4096, 1024, bp1, nullptr, nullptr, nullptr, hB);
  gemm_bt<64, 128, 1><<<dim3(16, 16), 256, 0, stream>>>(
      wp2t, hB, 2048, 4096, bp2, nullptr, a, wfilt, nullptr);

  // FFT conv (in-place over xnT)
  fft_filter<<<512, 256, 0, stream>>>(wfilt, wfh);
  fft_conv<<<dim3(512, 8), 256, 0, stream>>>(buf0, wfh, hidT);

  // stats + transpose + LN
  row_stats<<<dim3(32, 8), 256, 0, stream>>>(buf0, meanb, rstdb);
  untranspose_ln<<<dim3(16, 32, 8), 256, 0, stream>>>(buf0, meanb, rstdb, lng, lnb, znew, A1);

  // big FFN in two M-halves (H2 reuses buf0, dead after untranspose)
  for (int h = 0; h < 2; ++h) {
    const u16* Ap = A1 + (size_t)h * 8192 * 1024;
    const float* zp = znew + (size_t)h * 8192 * 1024;
    float* op = out + (size_t)h * 8192 * 1024;
    gemm_bt<128, 128, 0><<<dim3(32, 64), 256, 0, stream>>>(
        Ap, w1t, 4096, 1024, b1, nullptr, nullptr, nullptr, H2);
    gemm_bt<128, 128, 2><<<dim3(8, 64), 256, 0, stream>>>(
        H2, w2t, 1024, 4096, b2, zp, nullptr, op, nullptr);
  }
}